// Round 1
// baseline (923.024 us; speedup 1.0000x reference)
//
#include <hip/hip_runtime.h>
#include <math.h>

#define ND 256
#define ED 32
#define H1 5
#define NG 64

__device__ __forceinline__ float sigf(float z) {
    return 1.0f / (1.0f + __expf(-z));
}

__device__ __forceinline__ void atomAddF(float* p, float v) {
    // HW global_atomic_add_f32 on gfx90a+ regardless of -munsafe-fp-atomics
    unsafeAtomicAdd(p, v);
}

// ---------------------------------------------------------------------------
// Kernel 1: layer-1 node projections.
// Per node n: acc[0..4]=k, [5..9]=q, [10..14]=v -> kqv[n][16] (padded row);
//            acc[15..19] = x@Ws1 + b1 -> h[n][5]  (aggregation target).
// W index is wave-uniform (loop counter) -> scalar loads; x read divergent
// per-thread but lines fully consumed (row-major sequential per thread).
// ---------------------------------------------------------------------------
__global__ void node_proj1(const float* __restrict__ x,
                           const float* __restrict__ Wk, const float* __restrict__ bk,
                           const float* __restrict__ Wq, const float* __restrict__ bq,
                           const float* __restrict__ Wv, const float* __restrict__ bv,
                           const float* __restrict__ Ws, const float* __restrict__ br,
                           float* __restrict__ kqv, float* __restrict__ h, int N)
{
    int n = blockIdx.x * blockDim.x + threadIdx.x;
    if (n >= N) return;

    float acc[20];
#pragma unroll
    for (int c = 0; c < H1; c++) {
        acc[c]      = bk[c];
        acc[5 + c]  = bq[c];
        acc[10 + c] = bv[c];
        acc[15 + c] = br[c];
    }

    const float4* X4 = (const float4*)(x + (size_t)n * ND);
#pragma unroll 2
    for (int j4 = 0; j4 < ND / 4; j4++) {
        float4 xv = X4[j4];
        float xr[4] = {xv.x, xv.y, xv.z, xv.w};
#pragma unroll
        for (int r = 0; r < 4; r++) {
            int j = j4 * 4 + r;
#pragma unroll
            for (int c = 0; c < H1; c++) {
                acc[c]      += xr[r] * Wk[j * H1 + c];
                acc[5 + c]  += xr[r] * Wq[j * H1 + c];
                acc[10 + c] += xr[r] * Wv[j * H1 + c];
                acc[15 + c] += xr[r] * Ws[j * H1 + c];
            }
        }
    }

    float* kq = kqv + (size_t)n * 16;
#pragma unroll
    for (int c = 0; c < 15; c++) kq[c] = acc[c];
    kq[15] = 0.0f;
#pragma unroll
    for (int c = 0; c < H1; c++) h[(size_t)n * H1 + c] = acc[15 + c];
}

// ---------------------------------------------------------------------------
// Kernel 2: layer-1 edge pass. One thread per edge.
// e1[5] = ea@We1+be1, e2 = ea@We2+be2 (single edge_attr read for BOTH layers).
// gate = sigmoid(k[dst] + q[src] + 2*e1); msg = gate*(v[src]+e1);
// atomic-add msg into h[dst]; stash e2 for layer-2 edge pass.
// ---------------------------------------------------------------------------
__global__ void edge1(const float* __restrict__ ea, const int* __restrict__ ei,
                      const float* __restrict__ We1, const float* __restrict__ be1,
                      const float* __restrict__ We2, const float* __restrict__ be2,
                      const float* __restrict__ kqv, float* __restrict__ h,
                      float* __restrict__ e2buf, int E)
{
    int e = blockIdx.x * blockDim.x + threadIdx.x;
    if (e >= E) return;

    int s = ei[e];
    int d = ei[E + e];

    float acc[6];
#pragma unroll
    for (int c = 0; c < H1; c++) acc[c] = be1[c];
    acc[5] = be2[0];

    const float4* A4 = (const float4*)(ea + (size_t)e * ED);
#pragma unroll 2
    for (int j4 = 0; j4 < ED / 4; j4++) {
        float4 av = A4[j4];
        float ar[4] = {av.x, av.y, av.z, av.w};
#pragma unroll
        for (int r = 0; r < 4; r++) {
            int j = j4 * 4 + r;
#pragma unroll
            for (int c = 0; c < H1; c++) acc[c] += ar[r] * We1[j * H1 + c];
            acc[5] += ar[r] * We2[j];
        }
    }

    const float* kd = kqv + (size_t)d * 16;  // k at [0..4]
    const float* qs = kqv + (size_t)s * 16;  // q at [5..9], v at [10..14]

#pragma unroll
    for (int c = 0; c < H1; c++) {
        float g   = kd[c] + qs[5 + c] + 2.0f * acc[c];
        float msg = sigf(g) * (qs[10 + c] + acc[c]);
        atomAddF(&h[(size_t)d * H1 + c], msg);
    }
    e2buf[e] = acc[5];
}

// ---------------------------------------------------------------------------
// Kernel 3: GraphNorm stats. One block per group; batch_idx is SORTED so
// binary search gives [start,end) per group. No atomics. Single pass:
// var = E[h^2] - mean^2 * ms * (2 - ms).
// Emits per-(group,channel) affine: y = scale*h + shift.
// ---------------------------------------------------------------------------
__global__ void norm_reduce(const float* __restrict__ h, const int* __restrict__ B,
                            const float* __restrict__ gw, const float* __restrict__ gb,
                            const float* __restrict__ gms,
                            float* __restrict__ scale, float* __restrict__ shift, int N)
{
    int g = blockIdx.x;

    int lo = 0, hi = N;
    while (lo < hi) { int mid = (lo + hi) >> 1; if (B[mid] < g) lo = mid + 1; else hi = mid; }
    int start = lo;
    hi = N;
    while (lo < hi) { int mid = (lo + hi) >> 1; if (B[mid] < g + 1) lo = mid + 1; else hi = mid; }
    int end = lo;

    float sum[H1] = {0, 0, 0, 0, 0};
    float sq[H1]  = {0, 0, 0, 0, 0};
    for (int i = start + threadIdx.x; i < end; i += blockDim.x) {
#pragma unroll
        for (int c = 0; c < H1; c++) {
            float v = h[(size_t)i * H1 + c];
            sum[c] += v;
            sq[c]  += v * v;
        }
    }

#pragma unroll
    for (int off = 32; off >= 1; off >>= 1) {
#pragma unroll
        for (int c = 0; c < H1; c++) {
            sum[c] += __shfl_xor(sum[c], off);
            sq[c]  += __shfl_xor(sq[c], off);
        }
    }

    __shared__ float ls[4][2 * H1];
    int wave = threadIdx.x >> 6;
    int lane = threadIdx.x & 63;
    if (lane == 0) {
#pragma unroll
        for (int c = 0; c < H1; c++) { ls[wave][c] = sum[c]; ls[wave][H1 + c] = sq[c]; }
    }
    __syncthreads();

    if (threadIdx.x == 0) {
        float cnt = fmaxf((float)(end - start), 1.0f);
#pragma unroll
        for (int c = 0; c < H1; c++) {
            float s0 = ls[0][c] + ls[1][c] + ls[2][c] + ls[3][c];
            float q0 = ls[0][H1 + c] + ls[1][H1 + c] + ls[2][H1 + c] + ls[3][H1 + c];
            float mean = s0 / cnt;
            float ms   = gms[c];
            float var  = q0 / cnt - mean * mean * ms * (2.0f - ms);
            float inv  = rsqrtf(var + 1e-5f);
            float sc   = gw[c] * inv;
            scale[g * H1 + c] = sc;
            shift[g * H1 + c] = gb[c] - sc * mean * ms;
        }
    }
}

// ---------------------------------------------------------------------------
// Kernel 4: apply norm + ReLU, then layer-2 node projections (H1=5 -> H2=1).
// kqv2[n] = (k2, q2, v2, 0); out_acc[n] = h_rn @ Ws2 + b2 (aggregation target).
// ---------------------------------------------------------------------------
__global__ void norm_apply_proj2(const float* __restrict__ h, const int* __restrict__ B,
                                 const float* __restrict__ scale, const float* __restrict__ shift,
                                 const float* __restrict__ Wk2, const float* __restrict__ bk2,
                                 const float* __restrict__ Wq2, const float* __restrict__ bq2,
                                 const float* __restrict__ Wv2, const float* __restrict__ bv2,
                                 const float* __restrict__ Ws2, const float* __restrict__ b2,
                                 float4* __restrict__ kqv2, float* __restrict__ out_acc, int N)
{
    int n = blockIdx.x * blockDim.x + threadIdx.x;
    if (n >= N) return;

    int g = B[n];
    float k2 = bk2[0], q2 = bq2[0], v2 = bv2[0], s2 = b2[0];
#pragma unroll
    for (int c = 0; c < H1; c++) {
        float hn = scale[g * H1 + c] * h[(size_t)n * H1 + c] + shift[g * H1 + c];
        hn = fmaxf(hn, 0.0f);  // ReLU
        k2 += hn * Wk2[c];
        q2 += hn * Wq2[c];
        v2 += hn * Wv2[c];
        s2 += hn * Ws2[c];
    }
    kqv2[n]    = make_float4(k2, q2, v2, 0.0f);
    out_acc[n] = s2;
}

// ---------------------------------------------------------------------------
// Kernel 5: layer-2 edge pass using cached e2. One thread per edge, 1 atomic.
// ---------------------------------------------------------------------------
__global__ void edge2(const int* __restrict__ ei, const float* __restrict__ e2buf,
                      const float4* __restrict__ kqv2, float* __restrict__ out_acc, int E)
{
    int e = blockIdx.x * blockDim.x + threadIdx.x;
    if (e >= E) return;

    int s = ei[e];
    int d = ei[E + e];
    float ev = e2buf[e];
    float kd = kqv2[d].x;
    float4 sv = kqv2[s];
    float gt = sigf(kd + sv.y + 2.0f * ev);
    atomAddF(&out_acc[d], gt * (sv.z + ev));
}

// ---------------------------------------------------------------------------
// Kernel 6: final sigmoid (must run after ALL edge2 atomics).
// ---------------------------------------------------------------------------
__global__ void final_sig(const float* __restrict__ out_acc, float* __restrict__ out, int N)
{
    int n = blockIdx.x * blockDim.x + threadIdx.x;
    if (n < N) out[n] = sigf(out_acc[n]);
}

// ---------------------------------------------------------------------------
extern "C" void kernel_launch(void* const* d_in, const int* in_sizes, int n_in,
                              void* d_out, int out_size, void* d_ws, size_t ws_size,
                              hipStream_t stream)
{
    const float* x   = (const float*)d_in[0];
    const float* ea  = (const float*)d_in[1];
    const int*   ei  = (const int*)d_in[2];
    const int*   B   = (const int*)d_in[3];
    const float* Wk1 = (const float*)d_in[4];
    const float* bk1 = (const float*)d_in[5];
    const float* Wq1 = (const float*)d_in[6];
    const float* bq1 = (const float*)d_in[7];
    const float* Wv1 = (const float*)d_in[8];
    const float* bv1 = (const float*)d_in[9];
    const float* We1 = (const float*)d_in[10];
    const float* be1 = (const float*)d_in[11];
    const float* Ws1 = (const float*)d_in[12];
    const float* b1  = (const float*)d_in[13];
    const float* gw  = (const float*)d_in[14];
    const float* gb  = (const float*)d_in[15];
    const float* gms = (const float*)d_in[16];
    const float* Wk2 = (const float*)d_in[17];
    const float* bk2 = (const float*)d_in[18];
    const float* Wq2 = (const float*)d_in[19];
    const float* bq2 = (const float*)d_in[20];
    const float* Wv2 = (const float*)d_in[21];
    const float* bv2 = (const float*)d_in[22];
    const float* We2 = (const float*)d_in[23];
    const float* be2 = (const float*)d_in[24];
    const float* Ws2 = (const float*)d_in[25];
    const float* b2  = (const float*)d_in[26];

    const int N = in_sizes[0] / ND;   // 100000
    const int E = in_sizes[1] / ED;   // 1600000

    // Workspace layout (floats). Total ~4.2M floats (~16.8 MB).
    float* ws      = (float*)d_ws;
    float* kqv     = ws;                                  // N*16
    float* h       = kqv + (size_t)N * 16;                // N*5
    float* e2buf   = h + (size_t)N * H1;                  // E
    float* scale   = e2buf + (size_t)E;                   // NG*5
    float* shift   = scale + NG * H1;                     // NG*5
    float* kqv2f   = shift + NG * H1;                     // N*4 (float4-aligned: offset mult of 4)
    float* out_acc = kqv2f + (size_t)N * 4;               // N
    float4* kqv2   = (float4*)kqv2f;

    dim3 blk(256);
    dim3 gN((N + 255) / 256);
    dim3 gE((E + 255) / 256);

    node_proj1<<<gN, blk, 0, stream>>>(x, Wk1, bk1, Wq1, bq1, Wv1, bv1, Ws1, b1,
                                       kqv, h, N);
    edge1<<<gE, blk, 0, stream>>>(ea, ei, We1, be1, We2, be2, kqv, h, e2buf, E);
    norm_reduce<<<NG, blk, 0, stream>>>(h, B, gw, gb, gms, scale, shift, N);
    norm_apply_proj2<<<gN, blk, 0, stream>>>(h, B, scale, shift,
                                             Wk2, bk2, Wq2, bq2, Wv2, bv2, Ws2, b2,
                                             kqv2, out_acc, N);
    edge2<<<gE, blk, 0, stream>>>(ei, e2buf, kqv2, out_acc, E);
    final_sig<<<gN, blk, 0, stream>>>(out_acc, (float*)d_out, N);
}

// Round 2
// 870.008 us; speedup vs baseline: 1.0609x; 1.0609x over previous
//
#include <hip/hip_runtime.h>
#include <math.h>

#define ND 256
#define ED 32
#define H1 5
#define NG 64

__device__ __forceinline__ float sigf(float z) {
    return 1.0f / (1.0f + __expf(-z));
}

// ---------------------------------------------------------------------------
// Kernel 1: layer-1 node projections.
// kqv row layout (16 floats, 64B-aligned), chosen so the edge gathers are
// aligned float4s:
//   [0..4]=q, [5..9]=v, [10..14]=k, [15]=0
// h[n][0..4] = x@Ws1 + b1  (root term; aggregation adds into this later).
// ---------------------------------------------------------------------------
__global__ void node_proj1(const float* __restrict__ x,
                           const float* __restrict__ Wk, const float* __restrict__ bk,
                           const float* __restrict__ Wq, const float* __restrict__ bq,
                           const float* __restrict__ Wv, const float* __restrict__ bv,
                           const float* __restrict__ Ws, const float* __restrict__ br,
                           float* __restrict__ kqv, float* __restrict__ h, int N)
{
    int n = blockIdx.x * blockDim.x + threadIdx.x;
    if (n >= N) return;

    float acc[20];
#pragma unroll
    for (int c = 0; c < H1; c++) {
        acc[c]      = bk[c];   // k
        acc[5 + c]  = bq[c];   // q
        acc[10 + c] = bv[c];   // v
        acc[15 + c] = br[c];   // root
    }

    const float4* X4 = (const float4*)(x + (size_t)n * ND);
#pragma unroll 2
    for (int j4 = 0; j4 < ND / 4; j4++) {
        float4 xv = X4[j4];
        float xr[4] = {xv.x, xv.y, xv.z, xv.w};
#pragma unroll
        for (int r = 0; r < 4; r++) {
            int j = j4 * 4 + r;
#pragma unroll
            for (int c = 0; c < H1; c++) {
                acc[c]      += xr[r] * Wk[j * H1 + c];
                acc[5 + c]  += xr[r] * Wq[j * H1 + c];
                acc[10 + c] += xr[r] * Wv[j * H1 + c];
                acc[15 + c] += xr[r] * Ws[j * H1 + c];
            }
        }
    }

    float* row = kqv + (size_t)n * 16;
#pragma unroll
    for (int c = 0; c < H1; c++) {
        row[c]      = acc[5 + c];   // q
        row[5 + c]  = acc[10 + c];  // v
        row[10 + c] = acc[c];       // k
    }
    row[15] = 0.0f;
#pragma unroll
    for (int c = 0; c < H1; c++) h[(size_t)n * H1 + c] = acc[15 + c];
}

// ---------------------------------------------------------------------------
// Kernel 2: degree histogram over dst. Int atomics on a 400KB L2-hot array,
// fire-and-forget (no return value -> no dependent latency).
// ---------------------------------------------------------------------------
__global__ void hist_dst(const int* __restrict__ ei, int* __restrict__ cnt, int E)
{
    int e = blockIdx.x * blockDim.x + threadIdx.x;
    if (e < E) atomicAdd(&cnt[ei[E + e]], 1);
}

// ---------------------------------------------------------------------------
// Kernel 3: exclusive scan of cnt[N] -> offs[N+1], and a second copy into
// cursor[] for the scatter pass. Single 1024-thread block.
// ---------------------------------------------------------------------------
__global__ void scan_offs(const int* __restrict__ cnt, int* __restrict__ offs,
                          int* __restrict__ cursor, int N, int E)
{
    __shared__ int a[1024], b[1024];
    int t = threadIdx.x;
    int chunk = (N + 1023) >> 10;
    int lo = t * chunk;
    int hi = min(lo + chunk, N);

    int s = 0;
    for (int i = lo; i < hi; i++) s += cnt[i];
    a[t] = s;
    __syncthreads();

    int* in = a; int* out = b;
    for (int off = 1; off < 1024; off <<= 1) {
        out[t] = in[t] + ((t >= off) ? in[t - off] : 0);
        __syncthreads();
        int* tmp = in; in = out; out = tmp;
    }
    int run = in[t] - s;  // exclusive prefix of this thread's chunk

    for (int i = lo; i < hi; i++) {
        int c = cnt[i];
        offs[i] = run;
        cursor[i] = run;
        run += c;
    }
    if (t == 0) offs[N] = E;
}

// ---------------------------------------------------------------------------
// Kernel 4: edge projection + scatter into dst-sorted order.
// edge_attr staged through LDS (coalesced float4 global loads; 33-float row
// stride -> conflict-free readback). Record (32B): {src|int, e1[0..4], e2, 0}.
// ---------------------------------------------------------------------------
__global__ void edge_scatter(const float* __restrict__ ea, const int* __restrict__ ei,
                             const float* __restrict__ We1, const float* __restrict__ be1,
                             const float* __restrict__ We2, const float* __restrict__ be2,
                             int* __restrict__ cursor, float* __restrict__ sorted, int E)
{
    __shared__ float lds[256 * 33];
    int t = threadIdx.x;
    int base = blockIdx.x * 256;
    int nEdge = min(256, E - base);

    const float4* g = (const float4*)(ea + (size_t)base * ED);
    for (int k = t; k < nEdge * 8; k += 256) {
        float4 v = g[k];
        int f = k * 4;
        int r = f >> 5, c = f & 31;
        float* p = &lds[r * 33 + c];
        p[0] = v.x; p[1] = v.y; p[2] = v.z; p[3] = v.w;
    }
    __syncthreads();

    int e = base + t;
    if (e >= E) return;

    float acc0 = be1[0], acc1 = be1[1], acc2 = be1[2], acc3 = be1[3], acc4 = be1[4];
    float acc5 = be2[0];
    const float* myrow = &lds[t * 33];
#pragma unroll
    for (int j = 0; j < ED; j++) {
        float a = myrow[j];
        acc0 += a * We1[j * H1 + 0];
        acc1 += a * We1[j * H1 + 1];
        acc2 += a * We1[j * H1 + 2];
        acc3 += a * We1[j * H1 + 3];
        acc4 += a * We1[j * H1 + 4];
        acc5 += a * We2[j];
    }

    int s = ei[e];
    int d = ei[E + e];
    int pos = atomicAdd(&cursor[d], 1);

    float4* rec = (float4*)(sorted + (size_t)pos * 8);
    rec[0] = make_float4(__int_as_float(s), acc0, acc1, acc2);
    rec[1] = make_float4(acc3, acc4, acc5, 0.0f);
}

// ---------------------------------------------------------------------------
// Kernel 5: layer-1 aggregation. 16 lanes per node read the node's sorted
// edge segment coalesced; gather q/v of src (aligned float4s, L2-hot 6.4MB
// table); shfl-reduce within the 16-lane group; ONE plain write per node.
// ---------------------------------------------------------------------------
__global__ void aggregate1(const float* __restrict__ sorted, const int* __restrict__ offs,
                           const float* __restrict__ kqv, float* __restrict__ h, int N)
{
    int t = threadIdx.x;
    int n = blockIdx.x * 16 + (t >> 4);
    int lane = t & 15;
    if (n >= N) return;

    int start = offs[n], end = offs[n + 1];

    const float4* row = (const float4*)(kqv + (size_t)n * 16);
    float4 kA = row[2];  // v3 v4 k0 k1
    float4 kB = row[3];  // k2 k3 k4 0
    float kd0 = kA.z, kd1 = kA.w, kd2 = kB.x, kd3 = kB.y, kd4 = kB.z;

    float m0 = 0, m1 = 0, m2 = 0, m3 = 0, m4 = 0;
    for (int i = start + lane; i < end; i += 16) {
        const float4* rec = (const float4*)(sorted + (size_t)i * 8);
        float4 r0 = rec[0];  // src e10 e11 e12
        float4 r1 = rec[1];  // e13 e14 e2  0
        int s = __float_as_int(r0.x);
        const float4* srow = (const float4*)(kqv + (size_t)s * 16);
        float4 q0 = srow[0];  // q0 q1 q2 q3
        float4 q1 = srow[1];  // q4 v0 v1 v2
        float4 q2 = srow[2];  // v3 v4 k0 k1
        m0 += sigf(kd0 + q0.x + 2.0f * r0.y) * (q1.y + r0.y);
        m1 += sigf(kd1 + q0.y + 2.0f * r0.z) * (q1.z + r0.z);
        m2 += sigf(kd2 + q0.z + 2.0f * r0.w) * (q1.w + r0.w);
        m3 += sigf(kd3 + q0.w + 2.0f * r1.x) * (q2.x + r1.x);
        m4 += sigf(kd4 + q1.x + 2.0f * r1.y) * (q2.y + r1.y);
    }

#pragma unroll
    for (int off = 8; off >= 1; off >>= 1) {
        m0 += __shfl_xor(m0, off);
        m1 += __shfl_xor(m1, off);
        m2 += __shfl_xor(m2, off);
        m3 += __shfl_xor(m3, off);
        m4 += __shfl_xor(m4, off);
    }

    if (lane == 0) {
        size_t base = (size_t)n * H1;
        h[base + 0] += m0;  // h holds root term from node_proj1
        h[base + 1] += m1;
        h[base + 2] += m2;
        h[base + 3] += m3;
        h[base + 4] += m4;
    }
}

// ---------------------------------------------------------------------------
// Kernel 6: GraphNorm stats (unchanged — batch_idx sorted, binary search,
// no atomics). Emits per-(group,channel) affine y = scale*h + shift.
// ---------------------------------------------------------------------------
__global__ void norm_reduce(const float* __restrict__ h, const int* __restrict__ B,
                            const float* __restrict__ gw, const float* __restrict__ gb,
                            const float* __restrict__ gms,
                            float* __restrict__ scale, float* __restrict__ shift, int N)
{
    int g = blockIdx.x;

    int lo = 0, hi = N;
    while (lo < hi) { int mid = (lo + hi) >> 1; if (B[mid] < g) lo = mid + 1; else hi = mid; }
    int start = lo;
    hi = N;
    while (lo < hi) { int mid = (lo + hi) >> 1; if (B[mid] < g + 1) lo = mid + 1; else hi = mid; }
    int end = lo;

    float sum[H1] = {0, 0, 0, 0, 0};
    float sq[H1]  = {0, 0, 0, 0, 0};
    for (int i = start + threadIdx.x; i < end; i += blockDim.x) {
#pragma unroll
        for (int c = 0; c < H1; c++) {
            float v = h[(size_t)i * H1 + c];
            sum[c] += v;
            sq[c]  += v * v;
        }
    }

#pragma unroll
    for (int off = 32; off >= 1; off >>= 1) {
#pragma unroll
        for (int c = 0; c < H1; c++) {
            sum[c] += __shfl_xor(sum[c], off);
            sq[c]  += __shfl_xor(sq[c], off);
        }
    }

    __shared__ float ls[4][2 * H1];
    int wave = threadIdx.x >> 6;
    int lane = threadIdx.x & 63;
    if (lane == 0) {
#pragma unroll
        for (int c = 0; c < H1; c++) { ls[wave][c] = sum[c]; ls[wave][H1 + c] = sq[c]; }
    }
    __syncthreads();

    if (threadIdx.x == 0) {
        float cnt = fmaxf((float)(end - start), 1.0f);
#pragma unroll
        for (int c = 0; c < H1; c++) {
            float s0 = ls[0][c] + ls[1][c] + ls[2][c] + ls[3][c];
            float q0 = ls[0][H1 + c] + ls[1][H1 + c] + ls[2][H1 + c] + ls[3][H1 + c];
            float mean = s0 / cnt;
            float ms   = gms[c];
            float var  = q0 / cnt - mean * mean * ms * (2.0f - ms);
            float inv  = rsqrtf(var + 1e-5f);
            float sc   = gw[c] * inv;
            scale[g * H1 + c] = sc;
            shift[g * H1 + c] = gb[c] - sc * mean * ms;
        }
    }
}

// ---------------------------------------------------------------------------
// Kernel 7: apply norm + ReLU + layer-2 node projections.
// kqv2[n] = (k2, q2, v2, 0); root2[n] = h_rn @ Ws2 + b2.
// ---------------------------------------------------------------------------
__global__ void norm_apply_proj2(const float* __restrict__ h, const int* __restrict__ B,
                                 const float* __restrict__ scale, const float* __restrict__ shift,
                                 const float* __restrict__ Wk2, const float* __restrict__ bk2,
                                 const float* __restrict__ Wq2, const float* __restrict__ bq2,
                                 const float* __restrict__ Wv2, const float* __restrict__ bv2,
                                 const float* __restrict__ Ws2, const float* __restrict__ b2,
                                 float4* __restrict__ kqv2, float* __restrict__ root2, int N)
{
    int n = blockIdx.x * blockDim.x + threadIdx.x;
    if (n >= N) return;

    int g = B[n];
    float k2 = bk2[0], q2 = bq2[0], v2 = bv2[0], s2 = b2[0];
#pragma unroll
    for (int c = 0; c < H1; c++) {
        float hn = scale[g * H1 + c] * h[(size_t)n * H1 + c] + shift[g * H1 + c];
        hn = fmaxf(hn, 0.0f);
        k2 += hn * Wk2[c];
        q2 += hn * Wq2[c];
        v2 += hn * Wv2[c];
        s2 += hn * Ws2[c];
    }
    kqv2[n]   = make_float4(k2, q2, v2, 0.0f);
    root2[n]  = s2;
}

// ---------------------------------------------------------------------------
// Kernel 8: layer-2 aggregation + final sigmoid. Same sorted records (e2 at
// slot 6), kqv2 gathers are single aligned float4 from a 1.6MB L2-hot table.
// ---------------------------------------------------------------------------
__global__ void aggregate2(const float* __restrict__ sorted, const int* __restrict__ offs,
                           const float4* __restrict__ kqv2, const float* __restrict__ root2,
                           float* __restrict__ out, int N)
{
    int t = threadIdx.x;
    int n = blockIdx.x * 16 + (t >> 4);
    int lane = t & 15;
    if (n >= N) return;

    int start = offs[n], end = offs[n + 1];
    float kd = kqv2[n].x;

    float m = 0;
    for (int i = start + lane; i < end; i += 16) {
        const float4* rec = (const float4*)(sorted + (size_t)i * 8);
        float4 r0 = rec[0];
        float4 r1 = rec[1];
        int s = __float_as_int(r0.x);
        float e2 = r1.z;
        float4 sv = kqv2[s];
        m += sigf(kd + sv.y + 2.0f * e2) * (sv.z + e2);
    }

#pragma unroll
    for (int off = 8; off >= 1; off >>= 1) m += __shfl_xor(m, off);

    if (lane == 0) out[n] = sigf(root2[n] + m);
}

// ---------------------------------------------------------------------------
extern "C" void kernel_launch(void* const* d_in, const int* in_sizes, int n_in,
                              void* d_out, int out_size, void* d_ws, size_t ws_size,
                              hipStream_t stream)
{
    const float* x   = (const float*)d_in[0];
    const float* ea  = (const float*)d_in[1];
    const int*   ei  = (const int*)d_in[2];
    const int*   B   = (const int*)d_in[3];
    const float* Wk1 = (const float*)d_in[4];
    const float* bk1 = (const float*)d_in[5];
    const float* Wq1 = (const float*)d_in[6];
    const float* bq1 = (const float*)d_in[7];
    const float* Wv1 = (const float*)d_in[8];
    const float* bv1 = (const float*)d_in[9];
    const float* We1 = (const float*)d_in[10];
    const float* be1 = (const float*)d_in[11];
    const float* Ws1 = (const float*)d_in[12];
    const float* b1  = (const float*)d_in[13];
    const float* gw  = (const float*)d_in[14];
    const float* gb  = (const float*)d_in[15];
    const float* gms = (const float*)d_in[16];
    const float* Wk2 = (const float*)d_in[17];
    const float* bk2 = (const float*)d_in[18];
    const float* Wq2 = (const float*)d_in[19];
    const float* bq2 = (const float*)d_in[20];
    const float* Wv2 = (const float*)d_in[21];
    const float* bv2 = (const float*)d_in[22];
    const float* We2 = (const float*)d_in[23];
    const float* be2 = (const float*)d_in[24];
    const float* Ws2 = (const float*)d_in[25];
    const float* b2  = (const float*)d_in[26];

    const int N = in_sizes[0] / ND;   // 100000
    const int E = in_sizes[1] / ED;   // 1600000

    // Workspace layout (4B units). Total ~15.4M elems ~62MB.
    float* ws      = (float*)d_ws;
    float* kqv     = ws;                                   // N*16
    float* h       = kqv + (size_t)N * 16;                 // N*5
    float* sorted  = h + (size_t)N * H1;                   // E*8  (pad h end to keep 16B align: N*5=500000, *4B=2MB, sorted offset = N*21 floats = 8.4MB, 16B-aligned since N*21*4 % 16 == 0 (N mult of 4))
    int*   cnt     = (int*)(sorted + (size_t)E * 8);       // N
    int*   offs    = cnt + N;                              // N+1
    int*   cursor  = offs + N + 1;                         // N
    float* scale   = (float*)(cursor + N);                 // NG*5
    float* shift   = scale + NG * H1;                      // NG*5
    float* kqv2f   = shift + NG * H1;                      // N*4
    float* root2   = kqv2f + (size_t)N * 4;                // N
    float4* kqv2   = (float4*)kqv2f;

    dim3 blk(256);
    dim3 gN((N + 255) / 256);
    dim3 gE((E + 255) / 256);
    dim3 gAgg((N + 15) / 16);

    hipMemsetAsync(cnt, 0, (size_t)N * sizeof(int), stream);

    hist_dst<<<gE, blk, 0, stream>>>(ei, cnt, E);
    node_proj1<<<gN, blk, 0, stream>>>(x, Wk1, bk1, Wq1, bq1, Wv1, bv1, Ws1, b1,
                                       kqv, h, N);
    scan_offs<<<1, 1024, 0, stream>>>(cnt, offs, cursor, N, E);
    edge_scatter<<<gE, blk, 0, stream>>>(ea, ei, We1, be1, We2, be2, cursor, sorted, E);
    aggregate1<<<gAgg, blk, 0, stream>>>(sorted, offs, kqv, h, N);
    norm_reduce<<<NG, blk, 0, stream>>>(h, B, gw, gb, gms, scale, shift, N);
    norm_apply_proj2<<<gN, blk, 0, stream>>>(h, B, scale, shift,
                                             Wk2, bk2, Wq2, bq2, Wv2, bv2, Ws2, b2,
                                             kqv2, root2, N);
    aggregate2<<<gAgg, blk, 0, stream>>>(sorted, offs, kqv2, root2, (float*)d_out, N);
}

// Round 3
// 652.126 us; speedup vs baseline: 1.4154x; 1.3341x over previous
//
#include <hip/hip_runtime.h>
#include <math.h>

#define ND 256
#define ED 32
#define H1 5
#define NG 64
#define SCAN_TILE 1024

__device__ __forceinline__ float sigf(float z) {
    return 1.0f / (1.0f + __expf(-z));
}

// ---------------------------------------------------------------------------
// Kernel 1: layer-1 node projections.
// kqv row layout (16 floats, 64B-aligned): [0..4]=q, [5..9]=v, [10..14]=k, [15]=0
// h[n][0..4] = x@Ws1 + b1  (root term; aggregation adds into this later).
// ---------------------------------------------------------------------------
__global__ void node_proj1(const float* __restrict__ x,
                           const float* __restrict__ Wk, const float* __restrict__ bk,
                           const float* __restrict__ Wq, const float* __restrict__ bq,
                           const float* __restrict__ Wv, const float* __restrict__ bv,
                           const float* __restrict__ Ws, const float* __restrict__ br,
                           float* __restrict__ kqv, float* __restrict__ h, int N)
{
    int n = blockIdx.x * blockDim.x + threadIdx.x;
    if (n >= N) return;

    float acc[20];
#pragma unroll
    for (int c = 0; c < H1; c++) {
        acc[c]      = bk[c];   // k
        acc[5 + c]  = bq[c];   // q
        acc[10 + c] = bv[c];   // v
        acc[15 + c] = br[c];   // root
    }

    const float4* X4 = (const float4*)(x + (size_t)n * ND);
#pragma unroll 2
    for (int j4 = 0; j4 < ND / 4; j4++) {
        float4 xv = X4[j4];
        float xr[4] = {xv.x, xv.y, xv.z, xv.w};
#pragma unroll
        for (int r = 0; r < 4; r++) {
            int j = j4 * 4 + r;
#pragma unroll
            for (int c = 0; c < H1; c++) {
                acc[c]      += xr[r] * Wk[j * H1 + c];
                acc[5 + c]  += xr[r] * Wq[j * H1 + c];
                acc[10 + c] += xr[r] * Wv[j * H1 + c];
                acc[15 + c] += xr[r] * Ws[j * H1 + c];
            }
        }
    }

    float* row = kqv + (size_t)n * 16;
#pragma unroll
    for (int c = 0; c < H1; c++) {
        row[c]      = acc[5 + c];   // q
        row[5 + c]  = acc[10 + c];  // v
        row[10 + c] = acc[c];       // k
    }
    row[15] = 0.0f;
#pragma unroll
    for (int c = 0; c < H1; c++) h[(size_t)n * H1 + c] = acc[15 + c];
}

// ---------------------------------------------------------------------------
// Kernel 2: degree histogram over dst.
// ---------------------------------------------------------------------------
__global__ void hist_dst(const int* __restrict__ ei, int* __restrict__ cnt, int E)
{
    int e = blockIdx.x * blockDim.x + threadIdx.x;
    if (e < E) atomicAdd(&cnt[ei[E + e]], 1);
}

// ---------------------------------------------------------------------------
// Kernels 3a/3b/3c: parallel exclusive scan of cnt[N] -> offs[N+1] + cursor[N].
// 98 blocks x 1024-elem tiles, coalesced int4 I/O. Replaces the single-block
// scan whose stride-98 access serialized one CU's TA unit (231 us -> ~10 us).
// ---------------------------------------------------------------------------
__global__ void scan_part(const int* __restrict__ cnt, int* __restrict__ bsum, int N)
{
    int t = threadIdx.x;
    int base = blockIdx.x * SCAN_TILE + t * 4;
    int s = 0;
    if (base + 3 < N) {
        int4 v = *(const int4*)(cnt + base);
        s = v.x + v.y + v.z + v.w;
    } else {
        for (int i = 0; i < 4; i++) if (base + i < N) s += cnt[base + i];
    }
#pragma unroll
    for (int off = 32; off >= 1; off >>= 1) s += __shfl_xor(s, off);
    __shared__ int wsum[4];
    if ((t & 63) == 0) wsum[t >> 6] = s;
    __syncthreads();
    if (t == 0) bsum[blockIdx.x] = wsum[0] + wsum[1] + wsum[2] + wsum[3];
}

__global__ void scan_blocksums(int* __restrict__ bsum, int nb)
{
    // one block of 1024 threads; exclusive scan of bsum[nb] in place (nb<=1024)
    __shared__ int a[1024], b[1024];
    int t = threadIdx.x;
    int v = (t < nb) ? bsum[t] : 0;
    a[t] = v;
    __syncthreads();
    int* in = a; int* out = b;
    for (int off = 1; off < 1024; off <<= 1) {
        out[t] = in[t] + ((t >= off) ? in[t - off] : 0);
        __syncthreads();
        int* tmp = in; in = out; out = tmp;
    }
    if (t < nb) bsum[t] = in[t] - v;  // exclusive prefix
}

__global__ void scan_final(const int* __restrict__ cnt, const int* __restrict__ bsum,
                           int* __restrict__ offs, int* __restrict__ cursor, int N, int E)
{
    int t = threadIdx.x;
    int lane = t & 63;
    int wave = t >> 6;
    int base = blockIdx.x * SCAN_TILE + t * 4;

    int v0 = 0, v1 = 0, v2 = 0, v3 = 0;
    if (base + 3 < N) {
        int4 v = *(const int4*)(cnt + base);
        v0 = v.x; v1 = v.y; v2 = v.z; v3 = v.w;
    } else {
        if (base + 0 < N) v0 = cnt[base + 0];
        if (base + 1 < N) v1 = cnt[base + 1];
        if (base + 2 < N) v2 = cnt[base + 2];
        if (base + 3 < N) v3 = cnt[base + 3];
    }
    int s = v0 + v1 + v2 + v3;

    int inc = s;
#pragma unroll
    for (int off = 1; off < 64; off <<= 1) {
        int u = __shfl_up(inc, off);
        if (lane >= off) inc += u;
    }

    __shared__ int wtot[4];
    if (lane == 63) wtot[wave] = inc;
    __syncthreads();
    int woff = 0;
#pragma unroll
    for (int w = 0; w < 4; w++) woff += (w < wave) ? wtot[w] : 0;

    int excl = bsum[blockIdx.x] + woff + (inc - s);

    if (base < N) {
        int p0 = excl, p1 = p0 + v0, p2 = p1 + v1, p3 = p2 + v2;
        if (base + 3 < N) {
            *(int4*)(offs + base)   = make_int4(p0, p1, p2, p3);
            *(int4*)(cursor + base) = make_int4(p0, p1, p2, p3);
        } else {
            if (base + 0 < N) { offs[base + 0] = p0; cursor[base + 0] = p0; }
            if (base + 1 < N) { offs[base + 1] = p1; cursor[base + 1] = p1; }
            if (base + 2 < N) { offs[base + 2] = p2; cursor[base + 2] = p2; }
            if (base + 3 < N) { offs[base + 3] = p3; cursor[base + 3] = p3; }
        }
    }
    if (blockIdx.x == 0 && t == 0) offs[N] = E;
}

// ---------------------------------------------------------------------------
// Kernel 4: edge projection + scatter into dst-sorted order.
// edge_attr staged through LDS (coalesced float4 loads; 33-float row stride).
// Record (32B): {src|int, e1[0..4], e2, 0}.
// ---------------------------------------------------------------------------
__global__ void edge_scatter(const float* __restrict__ ea, const int* __restrict__ ei,
                             const float* __restrict__ We1, const float* __restrict__ be1,
                             const float* __restrict__ We2, const float* __restrict__ be2,
                             int* __restrict__ cursor, float* __restrict__ sorted, int E)
{
    __shared__ float lds[256 * 33];
    int t = threadIdx.x;
    int base = blockIdx.x * 256;
    int nEdge = min(256, E - base);

    const float4* g = (const float4*)(ea + (size_t)base * ED);
    for (int k = t; k < nEdge * 8; k += 256) {
        float4 v = g[k];
        int f = k * 4;
        int r = f >> 5, c = f & 31;
        float* p = &lds[r * 33 + c];
        p[0] = v.x; p[1] = v.y; p[2] = v.z; p[3] = v.w;
    }
    __syncthreads();

    int e = base + t;
    if (e >= E) return;

    float acc0 = be1[0], acc1 = be1[1], acc2 = be1[2], acc3 = be1[3], acc4 = be1[4];
    float acc5 = be2[0];
    const float* myrow = &lds[t * 33];
#pragma unroll
    for (int j = 0; j < ED; j++) {
        float a = myrow[j];
        acc0 += a * We1[j * H1 + 0];
        acc1 += a * We1[j * H1 + 1];
        acc2 += a * We1[j * H1 + 2];
        acc3 += a * We1[j * H1 + 3];
        acc4 += a * We1[j * H1 + 4];
        acc5 += a * We2[j];
    }

    int s = ei[e];
    int d = ei[E + e];
    int pos = atomicAdd(&cursor[d], 1);

    float4* rec = (float4*)(sorted + (size_t)pos * 8);
    rec[0] = make_float4(__int_as_float(s), acc0, acc1, acc2);
    rec[1] = make_float4(acc3, acc4, acc5, 0.0f);
}

// ---------------------------------------------------------------------------
// Kernel 5: layer-1 aggregation. 16 lanes per node, coalesced segment read,
// gather q/v of src from L2-hot kqv table, shfl-reduce, one write per node.
// ---------------------------------------------------------------------------
__global__ void aggregate1(const float* __restrict__ sorted, const int* __restrict__ offs,
                           const float* __restrict__ kqv, float* __restrict__ h, int N)
{
    int t = threadIdx.x;
    int n = blockIdx.x * 16 + (t >> 4);
    int lane = t & 15;
    if (n >= N) return;

    int start = offs[n], end = offs[n + 1];

    const float4* row = (const float4*)(kqv + (size_t)n * 16);
    float4 kA = row[2];  // v3 v4 k0 k1
    float4 kB = row[3];  // k2 k3 k4 0
    float kd0 = kA.z, kd1 = kA.w, kd2 = kB.x, kd3 = kB.y, kd4 = kB.z;

    float m0 = 0, m1 = 0, m2 = 0, m3 = 0, m4 = 0;
    for (int i = start + lane; i < end; i += 16) {
        const float4* rec = (const float4*)(sorted + (size_t)i * 8);
        float4 r0 = rec[0];  // src e10 e11 e12
        float4 r1 = rec[1];  // e13 e14 e2  0
        int s = __float_as_int(r0.x);
        const float4* srow = (const float4*)(kqv + (size_t)s * 16);
        float4 q0 = srow[0];  // q0 q1 q2 q3
        float4 q1 = srow[1];  // q4 v0 v1 v2
        float4 q2 = srow[2];  // v3 v4 k0 k1
        m0 += sigf(kd0 + q0.x + 2.0f * r0.y) * (q1.y + r0.y);
        m1 += sigf(kd1 + q0.y + 2.0f * r0.z) * (q1.z + r0.z);
        m2 += sigf(kd2 + q0.z + 2.0f * r0.w) * (q1.w + r0.w);
        m3 += sigf(kd3 + q0.w + 2.0f * r1.x) * (q2.x + r1.x);
        m4 += sigf(kd4 + q1.x + 2.0f * r1.y) * (q2.y + r1.y);
    }

#pragma unroll
    for (int off = 8; off >= 1; off >>= 1) {
        m0 += __shfl_xor(m0, off);
        m1 += __shfl_xor(m1, off);
        m2 += __shfl_xor(m2, off);
        m3 += __shfl_xor(m3, off);
        m4 += __shfl_xor(m4, off);
    }

    if (lane == 0) {
        size_t base = (size_t)n * H1;
        h[base + 0] += m0;  // h holds root term from node_proj1
        h[base + 1] += m1;
        h[base + 2] += m2;
        h[base + 3] += m3;
        h[base + 4] += m4;
    }
}

// ---------------------------------------------------------------------------
// Kernel 6: GraphNorm stats (batch_idx sorted, binary search, no atomics).
// ---------------------------------------------------------------------------
__global__ void norm_reduce(const float* __restrict__ h, const int* __restrict__ B,
                            const float* __restrict__ gw, const float* __restrict__ gb,
                            const float* __restrict__ gms,
                            float* __restrict__ scale, float* __restrict__ shift, int N)
{
    int g = blockIdx.x;

    int lo = 0, hi = N;
    while (lo < hi) { int mid = (lo + hi) >> 1; if (B[mid] < g) lo = mid + 1; else hi = mid; }
    int start = lo;
    hi = N;
    while (lo < hi) { int mid = (lo + hi) >> 1; if (B[mid] < g + 1) lo = mid + 1; else hi = mid; }
    int end = lo;

    float sum[H1] = {0, 0, 0, 0, 0};
    float sq[H1]  = {0, 0, 0, 0, 0};
    for (int i = start + threadIdx.x; i < end; i += blockDim.x) {
#pragma unroll
        for (int c = 0; c < H1; c++) {
            float v = h[(size_t)i * H1 + c];
            sum[c] += v;
            sq[c]  += v * v;
        }
    }

#pragma unroll
    for (int off = 32; off >= 1; off >>= 1) {
#pragma unroll
        for (int c = 0; c < H1; c++) {
            sum[c] += __shfl_xor(sum[c], off);
            sq[c]  += __shfl_xor(sq[c], off);
        }
    }

    __shared__ float ls[4][2 * H1];
    int wave = threadIdx.x >> 6;
    int lane = threadIdx.x & 63;
    if (lane == 0) {
#pragma unroll
        for (int c = 0; c < H1; c++) { ls[wave][c] = sum[c]; ls[wave][H1 + c] = sq[c]; }
    }
    __syncthreads();

    if (threadIdx.x == 0) {
        float cnt = fmaxf((float)(end - start), 1.0f);
#pragma unroll
        for (int c = 0; c < H1; c++) {
            float s0 = ls[0][c] + ls[1][c] + ls[2][c] + ls[3][c];
            float q0 = ls[0][H1 + c] + ls[1][H1 + c] + ls[2][H1 + c] + ls[3][H1 + c];
            float mean = s0 / cnt;
            float ms   = gms[c];
            float var  = q0 / cnt - mean * mean * ms * (2.0f - ms);
            float inv  = rsqrtf(var + 1e-5f);
            float sc   = gw[c] * inv;
            scale[g * H1 + c] = sc;
            shift[g * H1 + c] = gb[c] - sc * mean * ms;
        }
    }
}

// ---------------------------------------------------------------------------
// Kernel 7: apply norm + ReLU + layer-2 node projections.
// ---------------------------------------------------------------------------
__global__ void norm_apply_proj2(const float* __restrict__ h, const int* __restrict__ B,
                                 const float* __restrict__ scale, const float* __restrict__ shift,
                                 const float* __restrict__ Wk2, const float* __restrict__ bk2,
                                 const float* __restrict__ Wq2, const float* __restrict__ bq2,
                                 const float* __restrict__ Wv2, const float* __restrict__ bv2,
                                 const float* __restrict__ Ws2, const float* __restrict__ b2,
                                 float4* __restrict__ kqv2, float* __restrict__ root2, int N)
{
    int n = blockIdx.x * blockDim.x + threadIdx.x;
    if (n >= N) return;

    int g = B[n];
    float k2 = bk2[0], q2 = bq2[0], v2 = bv2[0], s2 = b2[0];
#pragma unroll
    for (int c = 0; c < H1; c++) {
        float hn = scale[g * H1 + c] * h[(size_t)n * H1 + c] + shift[g * H1 + c];
        hn = fmaxf(hn, 0.0f);
        k2 += hn * Wk2[c];
        q2 += hn * Wq2[c];
        v2 += hn * Wv2[c];
        s2 += hn * Ws2[c];
    }
    kqv2[n]  = make_float4(k2, q2, v2, 0.0f);
    root2[n] = s2;
}

// ---------------------------------------------------------------------------
// Kernel 8: layer-2 aggregation + final sigmoid.
// ---------------------------------------------------------------------------
__global__ void aggregate2(const float* __restrict__ sorted, const int* __restrict__ offs,
                           const float4* __restrict__ kqv2, const float* __restrict__ root2,
                           float* __restrict__ out, int N)
{
    int t = threadIdx.x;
    int n = blockIdx.x * 16 + (t >> 4);
    int lane = t & 15;
    if (n >= N) return;

    int start = offs[n], end = offs[n + 1];
    float kd = kqv2[n].x;

    float m = 0;
    for (int i = start + lane; i < end; i += 16) {
        const float4* rec = (const float4*)(sorted + (size_t)i * 8);
        float4 r0 = rec[0];
        float4 r1 = rec[1];
        int s = __float_as_int(r0.x);
        float e2 = r1.z;
        float4 sv = kqv2[s];
        m += sigf(kd + sv.y + 2.0f * e2) * (sv.z + e2);
    }

#pragma unroll
    for (int off = 8; off >= 1; off >>= 1) m += __shfl_xor(m, off);

    if (lane == 0) out[n] = sigf(root2[n] + m);
}

// ---------------------------------------------------------------------------
extern "C" void kernel_launch(void* const* d_in, const int* in_sizes, int n_in,
                              void* d_out, int out_size, void* d_ws, size_t ws_size,
                              hipStream_t stream)
{
    const float* x   = (const float*)d_in[0];
    const float* ea  = (const float*)d_in[1];
    const int*   ei  = (const int*)d_in[2];
    const int*   B   = (const int*)d_in[3];
    const float* Wk1 = (const float*)d_in[4];
    const float* bk1 = (const float*)d_in[5];
    const float* Wq1 = (const float*)d_in[6];
    const float* bq1 = (const float*)d_in[7];
    const float* Wv1 = (const float*)d_in[8];
    const float* bv1 = (const float*)d_in[9];
    const float* We1 = (const float*)d_in[10];
    const float* be1 = (const float*)d_in[11];
    const float* Ws1 = (const float*)d_in[12];
    const float* b1  = (const float*)d_in[13];
    const float* gw  = (const float*)d_in[14];
    const float* gb  = (const float*)d_in[15];
    const float* gms = (const float*)d_in[16];
    const float* Wk2 = (const float*)d_in[17];
    const float* bk2 = (const float*)d_in[18];
    const float* Wq2 = (const float*)d_in[19];
    const float* bq2 = (const float*)d_in[20];
    const float* Wv2 = (const float*)d_in[21];
    const float* bv2 = (const float*)d_in[22];
    const float* We2 = (const float*)d_in[23];
    const float* be2 = (const float*)d_in[24];
    const float* Ws2 = (const float*)d_in[25];
    const float* b2  = (const float*)d_in[26];

    const int N = in_sizes[0] / ND;   // 100000
    const int E = in_sizes[1] / ED;   // 1600000
    const int nb = (N + SCAN_TILE - 1) / SCAN_TILE;  // 98

    // Workspace layout (4B units), all segments 16B-aligned (N mult of 4).
    float* ws      = (float*)d_ws;
    float* kqv     = ws;                                   // N*16
    float* h       = kqv + (size_t)N * 16;                 // N*5
    float* sorted  = h + (size_t)N * H1;                   // E*8
    int*   cnt     = (int*)(sorted + (size_t)E * 8);       // N
    int*   offs    = cnt + N;                              // N+4 (pad keeps cursor 16B-aligned)
    int*   cursor  = offs + N + 4;                         // N
    int*   bsum    = cursor + N;                           // nb (<=1024), pad to 1024
    float* scale   = (float*)(bsum + 1024);                // NG*5
    float* shift   = scale + NG * H1;                      // NG*5
    float* kqv2f   = shift + NG * H1 + 2;                  // N*4 (pad +2 -> 16B-aligned: 320+320+2... )
    // NG*5=320 per array; 320+320=640, +2 pad = 642 ints from bsum end; ensure alignment:
    // bsum end is 16B-aligned (1024 ints). 642 % 4 != 0 -> fix: use +0 and realign below.
    kqv2f = (float*)(bsum + 1024) + 640;                   // 640 % 4 == 0 -> 16B-aligned
    float* root2   = kqv2f + (size_t)N * 4;                // N
    float4* kqv2   = (float4*)kqv2f;

    dim3 blk(256);
    dim3 gN((N + 255) / 256);
    dim3 gE((E + 255) / 256);
    dim3 gAgg((N + 15) / 16);

    hipMemsetAsync(cnt, 0, (size_t)N * sizeof(int), stream);

    hist_dst<<<gE, blk, 0, stream>>>(ei, cnt, E);
    node_proj1<<<gN, blk, 0, stream>>>(x, Wk1, bk1, Wq1, bq1, Wv1, bv1, Ws1, b1,
                                       kqv, h, N);
    scan_part<<<nb, 256, 0, stream>>>(cnt, bsum, N);
    scan_blocksums<<<1, 1024, 0, stream>>>(bsum, nb);
    scan_final<<<nb, 256, 0, stream>>>(cnt, bsum, offs, cursor, N, E);
    edge_scatter<<<gE, blk, 0, stream>>>(ea, ei, We1, be1, We2, be2, cursor, sorted, E);
    aggregate1<<<gAgg, blk, 0, stream>>>(sorted, offs, kqv, h, N);
    norm_reduce<<<NG, blk, 0, stream>>>(h, B, gw, gb, gms, scale, shift, N);
    norm_apply_proj2<<<gN, blk, 0, stream>>>(h, B, scale, shift,
                                             Wk2, bk2, Wq2, bq2, Wv2, bv2, Ws2, b2,
                                             kqv2, root2, N);
    aggregate2<<<gAgg, blk, 0, stream>>>(sorted, offs, kqv2, root2, (float*)d_out, N);
}